// Round 9
// baseline (41.946 us; speedup 1.0000x reference)
//
#include <hip/hip_runtime.h>

// SmoothSkeletonDual: exp-domain, register-strip + LDS boundary exchange.
// T'_0 = exp2(-x*C1); T'_{j+1} = box3x3(T'_j) (unnormalized).
// term_j = clip(-C2*log2(T'_j(p) * sum_{3x3} 1/T'_{j+1}(q)), 0, 1)
// skel = sum_{j=0}^{10} term_j
//
// Tile 64 cols x 72 rows (output 40x48, halo 12). 8 waves/block; wave w
// owns 9 rows in registers (lane = column). Horizontal neighbors: DPP
// wave shifts. Vertical halo (2 rows each side) via parity-double-buffered
// LDS, ONE barrier per iteration (parity buffer makes the trailing
// barrier redundant: a wave can only rewrite halo[p] at iter j+2 after
// barrier j+1, i.e. after all waves finished iter-j reads).
// Grid 26x22x2 = 1144 blocks -> ~4 blocks/CU, 8 waves/SIMD (vs 5.3 in R8).

#define HH 1024
#define WW 1024
#define NB 2
#define OTX 40
#define OTY 48
#define TH 72             // OTY + 24
#define RPW 9             // rows per wave
#define NW 8
#define HALO 12
#define GX 26             // ceil(1024/40)
#define GY 22             // ceil(1024/48)

constexpr float C1 = 28.85390081777927f;   // 1/(alpha*ln2)
constexpr float C2 = 0.03465735902799726f; // alpha*ln2

__device__ __forceinline__ int mir(int i, int n) {
    return i < 0 ? -i : (i >= n ? 2 * n - 2 - i : i);
}
// lane i <- lane i-1 (WAVE_SHR1 0x138; lane 0 zero-filled)
__device__ __forceinline__ float nbrL(float v) {
    return __int_as_float(__builtin_amdgcn_update_dpp(
        0, __float_as_int(v), 0x138, 0xf, 0xf, true));
}
// lane i <- lane i+1 (WAVE_SHL1 0x130; lane 63 zero-filled)
__device__ __forceinline__ float nbrR(float v) {
    return __int_as_float(__builtin_amdgcn_update_dpp(
        0, __float_as_int(v), 0x130, 0xf, 0xf, true));
}
__device__ __forceinline__ float hsum3(float v) { return nbrL(v) + v + nbrR(v); }
__device__ __forceinline__ float clamp01(float v) { return fminf(fmaxf(v, 0.f), 1.f); }

__global__ __launch_bounds__(512) void skel_k(const float* __restrict__ x0,
                                              float* __restrict__ out) {
    __shared__ float halo[2][NW][4][64];
    const int lane = threadIdx.x & 63;
    const int w    = threadIdx.x >> 6;
    const int tx = blockIdx.x, ty = blockIdx.y, b = blockIdx.z;
    const int gx0 = tx * OTX - HALO, gy0 = ty * OTY - HALO;
    const int r0 = w * RPW;          // first owned tile-row

    const float* src = x0 + (size_t)b * HH * WW;
    const int mx = mir(gx0 + lane, WW);

    // load owned rows: A[i] = exp2(-x * C1)
    float A[RPW];
    #pragma unroll
    for (int i = 0; i < RPW; ++i) {
        int my = mir(gy0 + r0 + i, HH);
        A[i] = __builtin_amdgcn_exp2f(src[(size_t)my * WW + mx] * -C1);
    }

    float sk[RPW];
    #pragma unroll
    for (int i = 0; i < RPW; ++i) sk[i] = 0.f;

    #pragma unroll 1
    for (int j = 0; j < 11; ++j) {
        const int p = j & 1;
        // exchange boundary rows (O local {0,1,RPW-2,RPW-1})
        halo[p][w][0][lane] = A[0];
        halo[p][w][1][lane] = A[1];
        halo[p][w][2][lane] = A[RPW - 2];
        halo[p][w][3][lane] = A[RPW - 1];
        __syncthreads();
        float hm2 = (w > 0)      ? halo[p][w - 1][2][lane] : 1.0f;  // O[-2]
        float hm1 = (w > 0)      ? halo[p][w - 1][3][lane] : 1.0f;  // O[-1]
        float hp0 = (w < NW - 1) ? halo[p][w + 1][0][lane] : 1.0f;  // O[RPW]
        float hp1 = (w < NW - 1) ? halo[p][w + 1][1][lane] : 1.0f;  // O[RPW+1]

        // rolling sweep, k = -1..RPW: N[k] = vsum3(hsum3(O[k-1..k+1]));
        // hr[k] = hsum3(rcp(N[k])); term t=k-1 uses O[t], hr[t-1..t+1].
        float h_m = hsum3(hm2);
        float h_c = hsum3(hm1);
        float r_2 = 0.f, r_1 = 0.f;   // hr[k-2], hr[k-1]
        float n_prev = 0.f;           // N[k-1]
        #pragma unroll
        for (int k = -1; k <= RPW; ++k) {
            float oext = (k + 1 <= RPW - 1) ? A[k + 1 < 0 ? 0 : k + 1]
                         : (k + 1 == RPW ? hp0 : hp1);   // O[k+1] (static)
            float h_p = hsum3(oext);
            float n   = h_m + h_c + h_p;                 // N[k]
            float r_0 = hsum3(__builtin_amdgcn_rcpf(n)); // hr[k]
            if (k >= 1) {
                int t = k - 1;                           // term row (local)
                int trow = r0 + t;
                if (trow >= HALO && trow < TH - HALO) {
                    float v = -C2 * __builtin_amdgcn_logf(A[t] * (r_2 + r_1 + r_0));
                    sk[t] += clamp01(v);
                }
                A[t] = n_prev;                           // O[t] <- N[t]
            }
            n_prev = n;
            h_m = h_c; h_c = h_p;
            r_2 = r_1; r_1 = r_0;
        }
        // no trailing barrier: parity buffer + next iter's barrier suffice
    }

    // store output: lanes 12..51, owned rows in [12, TH-12)
    if (lane >= HALO && lane < HALO + OTX) {
        int gx = tx * OTX + lane - HALO;
        if (gx < WW) {
            float* dst = out + (size_t)b * HH * WW;
            #pragma unroll
            for (int i = 0; i < RPW; ++i) {
                int trow = r0 + i;
                int gy = gy0 + trow;
                if (trow >= HALO && trow < TH - HALO && gy < HH)
                    dst[(size_t)gy * WW + gx] = sk[i];
            }
        }
    }
}

extern "C" void kernel_launch(void* const* d_in, const int* in_sizes, int n_in,
                              void* d_out, int out_size, void* d_ws, size_t ws_size,
                              hipStream_t stream) {
    const float* x0 = (const float*)d_in[0];
    float* skel = (float*)d_out;
    skel_k<<<dim3(GX, GY, NB), dim3(512, 1, 1), 0, stream>>>(x0, skel);
}

// Round 10
// 41.740 us; speedup vs baseline: 1.0049x; 1.0049x over previous
//
#include <hip/hip_runtime.h>

// SmoothSkeletonDual: exp-domain, register-strip + LDS boundary exchange.
// T'_0 = exp2(-x*C1); T'_{j+1} = box3x3(T'_j) (unnormalized).
// term_j = clip(-C2*log2(T'_j(p) * sum_{3x3} 1/T'_{j+1}(q)), 0, 1)
// skel = sum_{j=0}^{10} term_j
//
// Tile 64 cols x 72 rows (output 40x48, halo 12). 8 waves/block; wave w
// owns 9 rows in registers (lane = column). Horizontal neighbors: DPP
// wave shifts. Vertical halo (2 rows each side) via parity-double-buffered
// LDS, ONE barrier per iteration.
// __launch_bounds__(512, 8): pin VGPR budget to 64/lane — R9's build chose
// VGPR_Count=24 and spilled A[]/sk[] to scratch (occupancy capped at 49%).

#define HH 1024
#define WW 1024
#define NB 2
#define OTX 40
#define OTY 48
#define TH 72             // OTY + 24
#define RPW 9             // rows per wave
#define NW 8
#define HALO 12
#define GX 26             // ceil(1024/40)
#define GY 22             // ceil(1024/48)

constexpr float C1 = 28.85390081777927f;   // 1/(alpha*ln2)
constexpr float C2 = 0.03465735902799726f; // alpha*ln2

__device__ __forceinline__ int mir(int i, int n) {
    return i < 0 ? -i : (i >= n ? 2 * n - 2 - i : i);
}
// lane i <- lane i-1 (WAVE_SHR1 0x138; lane 0 zero-filled)
__device__ __forceinline__ float nbrL(float v) {
    return __int_as_float(__builtin_amdgcn_update_dpp(
        0, __float_as_int(v), 0x138, 0xf, 0xf, true));
}
// lane i <- lane i+1 (WAVE_SHL1 0x130; lane 63 zero-filled)
__device__ __forceinline__ float nbrR(float v) {
    return __int_as_float(__builtin_amdgcn_update_dpp(
        0, __float_as_int(v), 0x130, 0xf, 0xf, true));
}
__device__ __forceinline__ float hsum3(float v) { return nbrL(v) + v + nbrR(v); }
__device__ __forceinline__ float clamp01(float v) { return fminf(fmaxf(v, 0.f), 1.f); }

__global__ __launch_bounds__(512, 8) void skel_k(const float* __restrict__ x0,
                                                 float* __restrict__ out) {
    __shared__ float halo[2][NW][4][64];
    const int lane = threadIdx.x & 63;
    const int w    = threadIdx.x >> 6;
    const int tx = blockIdx.x, ty = blockIdx.y, b = blockIdx.z;
    const int gx0 = tx * OTX - HALO, gy0 = ty * OTY - HALO;
    const int r0 = w * RPW;          // first owned tile-row

    const float* src = x0 + (size_t)b * HH * WW;
    const int mx = mir(gx0 + lane, WW);

    // load owned rows: A[i] = exp2(-x * C1)
    float A[RPW];
    #pragma unroll
    for (int i = 0; i < RPW; ++i) {
        int my = mir(gy0 + r0 + i, HH);
        A[i] = __builtin_amdgcn_exp2f(src[(size_t)my * WW + mx] * -C1);
    }

    float sk[RPW];
    #pragma unroll
    for (int i = 0; i < RPW; ++i) sk[i] = 0.f;

    #pragma unroll 1
    for (int j = 0; j < 11; ++j) {
        const int p = j & 1;
        // exchange boundary rows (O local {0,1,RPW-2,RPW-1})
        halo[p][w][0][lane] = A[0];
        halo[p][w][1][lane] = A[1];
        halo[p][w][2][lane] = A[RPW - 2];
        halo[p][w][3][lane] = A[RPW - 1];
        __syncthreads();
        float hm2 = (w > 0)      ? halo[p][w - 1][2][lane] : 1.0f;  // O[-2]
        float hm1 = (w > 0)      ? halo[p][w - 1][3][lane] : 1.0f;  // O[-1]
        float hp0 = (w < NW - 1) ? halo[p][w + 1][0][lane] : 1.0f;  // O[RPW]
        float hp1 = (w < NW - 1) ? halo[p][w + 1][1][lane] : 1.0f;  // O[RPW+1]

        // rolling sweep, k = -1..RPW: N[k] = vsum3(hsum3(O[k-1..k+1]));
        // hr[k] = hsum3(rcp(N[k])); term t=k-1 uses O[t], hr[t-1..t+1].
        float h_m = hsum3(hm2);
        float h_c = hsum3(hm1);
        float r_2 = 0.f, r_1 = 0.f;   // hr[k-2], hr[k-1]
        float n_prev = 0.f;           // N[k-1]
        #pragma unroll
        for (int k = -1; k <= RPW; ++k) {
            float oext = (k + 1 <= RPW - 1) ? A[k + 1 < 0 ? 0 : k + 1]
                         : (k + 1 == RPW ? hp0 : hp1);   // O[k+1] (static)
            float h_p = hsum3(oext);
            float n   = h_m + h_c + h_p;                 // N[k]
            float r_0 = hsum3(__builtin_amdgcn_rcpf(n)); // hr[k]
            if (k >= 1) {
                int t = k - 1;                           // term row (local)
                int trow = r0 + t;
                if (trow >= HALO && trow < TH - HALO) {
                    float v = -C2 * __builtin_amdgcn_logf(A[t] * (r_2 + r_1 + r_0));
                    sk[t] += clamp01(v);
                }
                A[t] = n_prev;                           // O[t] <- N[t]
            }
            n_prev = n;
            h_m = h_c; h_c = h_p;
            r_2 = r_1; r_1 = r_0;
        }
        // no trailing barrier: parity buffer + next iter's barrier suffice
    }

    // store output: lanes 12..51, owned rows in [12, TH-12)
    if (lane >= HALO && lane < HALO + OTX) {
        int gx = tx * OTX + lane - HALO;
        if (gx < WW) {
            float* dst = out + (size_t)b * HH * WW;
            #pragma unroll
            for (int i = 0; i < RPW; ++i) {
                int trow = r0 + i;
                int gy = gy0 + trow;
                if (trow >= HALO && trow < TH - HALO && gy < HH)
                    dst[(size_t)gy * WW + gx] = sk[i];
            }
        }
    }
}

extern "C" void kernel_launch(void* const* d_in, const int* in_sizes, int n_in,
                              void* d_out, int out_size, void* d_ws, size_t ws_size,
                              hipStream_t stream) {
    const float* x0 = (const float*)d_in[0];
    float* skel = (float*)d_out;
    skel_k<<<dim3(GX, GY, NB), dim3(512, 1, 1), 0, stream>>>(x0, skel);
}

// Round 11
// 40.734 us; speedup vs baseline: 1.0297x; 1.0247x over previous
//
#include <hip/hip_runtime.h>

// SmoothSkeletonDual: exp-domain, register-strip + LDS boundary exchange.
// T'_0 = exp2(-x*C1); T'_{j+1} = box3x3(T'_j) (unnormalized).
// term_j = clip(-C2*log2(T'_j(p) * sum_{3x3} 1/T'_{j+1}(q)), 0, 1)
// skel = sum_{j=0}^{10} term_j
//
// Tile 64 cols x 72 rows (output 40x48, halo 12). 8 waves/block; wave w
// owns 9 rows as NAMED SCALARS a0..a8 (R9/R10 used float A[9]: compiler
// demoted it to scratch -> VGPR_Count=24, occupancy 49%, 42us). The
// 11-step rolling sweep is macro-expanded with static names -- no
// indexable arrays exist in the kernel, so everything must be VGPRs.
// Horizontal neighbors: DPP wave shifts. Vertical halo (2 rows/side) via
// parity-double-buffered LDS, one barrier per iteration.

#define HH 1024
#define WW 1024
#define NB 2
#define OTX 40
#define OTY 48
#define TH 72             // OTY + 24
#define RPW 9             // rows per wave
#define NW 8
#define HALO 12
#define GX 26             // ceil(1024/40)
#define GY 22             // ceil(1024/48)

constexpr float C1 = 28.85390081777927f;   // 1/(alpha*ln2)
constexpr float C2 = 0.03465735902799726f; // alpha*ln2

__device__ __forceinline__ int mir(int i, int n) {
    return i < 0 ? -i : (i >= n ? 2 * n - 2 - i : i);
}
// lane i <- lane i-1 (WAVE_SHR1 0x138; lane 0 zero-filled)
__device__ __forceinline__ float nbrL(float v) {
    return __int_as_float(__builtin_amdgcn_update_dpp(
        0, __float_as_int(v), 0x138, 0xf, 0xf, true));
}
// lane i <- lane i+1 (WAVE_SHL1 0x130; lane 63 zero-filled)
__device__ __forceinline__ float nbrR(float v) {
    return __int_as_float(__builtin_amdgcn_update_dpp(
        0, __float_as_int(v), 0x130, 0xf, 0xf, true));
}
__device__ __forceinline__ float hsum3(float v) { return nbrL(v) + v + nbrR(v); }
__device__ __forceinline__ float clamp01(float v) { return fminf(fmaxf(v, 0.f), 1.f); }

__global__ __launch_bounds__(512, 8) void skel_k(const float* __restrict__ x0,
                                                 float* __restrict__ out) {
    __shared__ float halo[2][NW][4][64];
    const int lane = threadIdx.x & 63;
    const int w    = threadIdx.x >> 6;
    const int tx = blockIdx.x, ty = blockIdx.y, b = blockIdx.z;
    const int gx0 = tx * OTX - HALO, gy0 = ty * OTY - HALO;
    const int r0 = w * RPW;          // first owned tile-row

    const float* src = x0 + (size_t)b * HH * WW;
    const int mx = mir(gx0 + lane, WW);

    // owned rows as named scalars
    float a0, a1, a2, a3, a4, a5, a6, a7, a8;
#define LOADROW(I, AV) { int my_ = mir(gy0 + r0 + (I), HH); \
    AV = __builtin_amdgcn_exp2f(src[(size_t)my_ * WW + mx] * -C1); }
    LOADROW(0, a0) LOADROW(1, a1) LOADROW(2, a2) LOADROW(3, a3) LOADROW(4, a4)
    LOADROW(5, a5) LOADROW(6, a6) LOADROW(7, a7) LOADROW(8, a8)
#undef LOADROW

    float s0 = 0.f, s1 = 0.f, s2 = 0.f, s3 = 0.f, s4 = 0.f,
          s5 = 0.f, s6 = 0.f, s7 = 0.f, s8 = 0.f;

    // wave-uniform per-row term masks (rows with output: [12, 60))
#define OKT(I) ((r0 + (I) >= HALO) && (r0 + (I) < TH - HALO))
    const bool ok0 = OKT(0), ok1 = OKT(1), ok2 = OKT(2), ok3 = OKT(3),
               ok4 = OKT(4), ok5 = OKT(5), ok6 = OKT(6), ok7 = OKT(7),
               ok8 = OKT(8);
#undef OKT

    #pragma unroll 1
    for (int j = 0; j < 11; ++j) {
        const int p = j & 1;
        halo[p][w][0][lane] = a0;
        halo[p][w][1][lane] = a1;
        halo[p][w][2][lane] = a7;
        halo[p][w][3][lane] = a8;
        __syncthreads();
        float hm2 = (w > 0)      ? halo[p][w - 1][2][lane] : 1.0f;  // O[-2]
        float hm1 = (w > 0)      ? halo[p][w - 1][3][lane] : 1.0f;  // O[-1]
        float hp0 = (w < NW - 1) ? halo[p][w + 1][0][lane] : 1.0f;  // O[9]
        float hp1 = (w < NW - 1) ? halo[p][w + 1][1][lane] : 1.0f;  // O[10]

        // rolling sweep, 11 static steps (k=-1..9):
        // N[k] = vsum3(hsum3(O[k-1..k+1])); hr[k] = hsum3(rcp(N[k]));
        // term t=k-1: s_t += clip(-C2*log2(a_t*(hr[t-1]+hr[t]+hr[t+1])));
        // then a_t <- N[t] (box update, one iteration behind).
        float h_m = hsum3(hm2);
        float h_c = hsum3(hm1);
        float r_2 = 0.f, r_1 = 0.f, n_prev = 0.f;

#define STEP0(OP1) { \
        float h_p = hsum3(OP1); \
        float n   = h_m + h_c + h_p; \
        float r_0 = hsum3(__builtin_amdgcn_rcpf(n)); \
        n_prev = n; h_m = h_c; h_c = h_p; r_2 = r_1; r_1 = r_0; }

#define STEP(OP1, AT, ST, OKT) { \
        float h_p = hsum3(OP1); \
        float n   = h_m + h_c + h_p; \
        float r_0 = hsum3(__builtin_amdgcn_rcpf(n)); \
        if (OKT) ST += clamp01(-C2 * __builtin_amdgcn_logf(AT * (r_2 + r_1 + r_0))); \
        AT = n_prev; \
        n_prev = n; h_m = h_c; h_c = h_p; r_2 = r_1; r_1 = r_0; }

        STEP0(a0)                  // k=-1
        STEP0(a1)                  // k=0
        STEP(a2,  a0, s0, ok0)     // k=1
        STEP(a3,  a1, s1, ok1)
        STEP(a4,  a2, s2, ok2)
        STEP(a5,  a3, s3, ok3)
        STEP(a6,  a4, s4, ok4)
        STEP(a7,  a5, s5, ok5)
        STEP(a8,  a6, s6, ok6)
        STEP(hp0, a7, s7, ok7)
        STEP(hp1, a8, s8, ok8)     // k=9
#undef STEP0
#undef STEP
        // no trailing barrier: parity buffer + next iter's barrier suffice
    }

    // store output: lanes 12..51 -> cols, owned rows intersect [12, 60)
    if (lane >= HALO && lane < HALO + OTX) {
        int gx = tx * OTX + lane - HALO;
        if (gx < WW) {
            float* dst = out + (size_t)b * HH * WW;
#define STOREROW(I, SV) { int trow = r0 + (I); int gy = gy0 + trow; \
            if (trow >= HALO && trow < TH - HALO && gy < HH) \
                dst[(size_t)gy * WW + gx] = SV; }
            STOREROW(0, s0) STOREROW(1, s1) STOREROW(2, s2) STOREROW(3, s3)
            STOREROW(4, s4) STOREROW(5, s5) STOREROW(6, s6) STOREROW(7, s7)
            STOREROW(8, s8)
#undef STOREROW
        }
    }
}

extern "C" void kernel_launch(void* const* d_in, const int* in_sizes, int n_in,
                              void* d_out, int out_size, void* d_ws, size_t ws_size,
                              hipStream_t stream) {
    const float* x0 = (const float*)d_in[0];
    float* skel = (float*)d_out;
    skel_k<<<dim3(GX, GY, NB), dim3(512, 1, 1), 0, stream>>>(x0, skel);
}

// Round 12
// 35.872 us; speedup vs baseline: 1.1693x; 1.1355x over previous
//
#include <hip/hip_runtime.h>

// SmoothSkeletonDual: exp-domain, packed-FP32 (2 cols/lane) register-strip.
// T'_0 = exp2(-x*C1); T'_{j+1} = box3x3(T'_j) (unnormalized).
// term_j = clip(-C2*log2(T'_j(p) * sum_{3x3} 1/T'_{j+1}(q)), 0, 1)
// skel = sum_{j=0}^{10} term_j
//
// Tile 128 cols x 56 rows (output 104x32, halo 12). 8 waves/block; wave w
// owns 7 rows; each LANE owns 2 adjacent cols as f32x2 -> v_pk_add_f32 /
// v_pk_mul_f32 (inline asm; full-rate packed FP32) halve the VALU stream.
// Horizontal 3-tap: 2 DPP shifts (hi of lane-1, lo of lane+1) + op_sel-
// swapped pk_add. Vertical halo (2 rows/side) via parity-double-buffered
// LDS (f32x2, ds_*_b64), one barrier per iteration.

#define HH 1024
#define WW 1024
#define NB 2
#define OTX 104
#define OTY 32
#define TW 128
#define TH 56             // RPW*NW
#define RPW 7
#define NW 8
#define HALO 12
#define GX 10             // ceil(1024/104)
#define GY 32             // 1024/32 exact

constexpr float C1 = 28.85390081777927f;   // 1/(alpha*ln2)
constexpr float C2 = 0.03465735902799726f; // alpha*ln2

typedef float f32x2 __attribute__((ext_vector_type(2)));

__device__ __forceinline__ int mir(int i, int n) {
    return i < 0 ? -i : (i >= n ? 2 * n - 2 - i : i);
}
// lane i <- lane i-1 (WAVE_SHR1 0x138; lane 0 zero-filled)
__device__ __forceinline__ float nbrL(float v) {
    return __int_as_float(__builtin_amdgcn_update_dpp(
        0, __float_as_int(v), 0x138, 0xf, 0xf, true));
}
// lane i <- lane i+1 (WAVE_SHL1 0x130; lane 63 zero-filled)
__device__ __forceinline__ float nbrR(float v) {
    return __int_as_float(__builtin_amdgcn_update_dpp(
        0, __float_as_int(v), 0x130, 0xf, 0xf, true));
}

__device__ __forceinline__ f32x2 pk_add(f32x2 a, f32x2 b) {
    f32x2 d;
    asm("v_pk_add_f32 %0, %1, %2" : "=v"(d) : "v"(a), "v"(b));
    return d;
}
// d = a + swap(b):  d.lo = a.lo + b.hi ; d.hi = a.hi + b.lo
__device__ __forceinline__ f32x2 pk_add_swapB(f32x2 a, f32x2 b) {
    f32x2 d;
    asm("v_pk_add_f32 %0, %1, %2 op_sel:[0,1] op_sel_hi:[1,0]"
        : "=v"(d) : "v"(a), "v"(b));
    return d;
}
__device__ __forceinline__ f32x2 pk_mul(f32x2 a, f32x2 b) {
    f32x2 d;
    asm("v_pk_mul_f32 %0, %1, %2" : "=v"(d) : "v"(a), "v"(b));
    return d;
}

// 3-tap horizontal sum of the 128-col row: lane holds cols (2i, 2i+1).
// out.lo = c(2i-1)+c(2i)+c(2i+1); out.hi = c(2i)+c(2i+1)+c(2i+2).
__device__ __forceinline__ f32x2 hsum3p(f32x2 P) {
    f32x2 LR;
    LR.x = nbrL(P.y);                 // c(2i-1)
    LR.y = nbrR(P.x);                 // c(2i+2)
    f32x2 X = pk_add(LR, P);          // (L+lo, R+hi)
    return pk_add_swapB(X, P);        // (L+lo+hi, R+hi+lo)
}

__global__ __launch_bounds__(512, 5) void skel_k(const float* __restrict__ x0,
                                                 float* __restrict__ out) {
    __shared__ f32x2 halo[2][NW][4][64];
    const int lane = threadIdx.x & 63;
    const int w    = threadIdx.x >> 6;
    const int tx = blockIdx.x, ty = blockIdx.y, b = blockIdx.z;
    const int gx0 = tx * OTX - HALO, gy0 = ty * OTY - HALO;
    const int r0 = w * RPW;          // first owned tile-row

    const float* src = x0 + (size_t)b * HH * WW;
    const int mx0 = mir(gx0 + 2 * lane, WW);
    const int mx1 = mir(gx0 + 2 * lane + 1, WW);

    // owned rows (f32x2), named scalars
    f32x2 a0, a1, a2, a3, a4, a5, a6;
#define LOADROW(I, AV) { int my_ = mir(gy0 + r0 + (I), HH); \
    const float* rr_ = src + (size_t)my_ * WW; \
    AV.x = __builtin_amdgcn_exp2f(rr_[mx0] * -C1); \
    AV.y = __builtin_amdgcn_exp2f(rr_[mx1] * -C1); }
    LOADROW(0, a0) LOADROW(1, a1) LOADROW(2, a2) LOADROW(3, a3)
    LOADROW(4, a4) LOADROW(5, a5) LOADROW(6, a6)
#undef LOADROW

    f32x2 s0 = {0.f, 0.f}, s1 = s0, s2 = s0, s3 = s0, s4 = s0,
          s5 = s0, s6 = s0;

    // wave-uniform per-row term masks (term rows: [12, 44))
#define OKT(I) ((r0 + (I) >= HALO) && (r0 + (I) < TH - HALO))
    const bool ok0 = OKT(0), ok1 = OKT(1), ok2 = OKT(2), ok3 = OKT(3),
               ok4 = OKT(4), ok5 = OKT(5), ok6 = OKT(6);
#undef OKT

    #pragma unroll 1
    for (int j = 0; j < 11; ++j) {
        const int p = j & 1;
        halo[p][w][0][lane] = a0;
        halo[p][w][1][lane] = a1;
        halo[p][w][2][lane] = a5;
        halo[p][w][3][lane] = a6;
        __syncthreads();
        f32x2 one2 = {1.f, 1.f};
        f32x2 hm2 = (w > 0)      ? halo[p][w - 1][2][lane] : one2;  // O[-2]
        f32x2 hm1 = (w > 0)      ? halo[p][w - 1][3][lane] : one2;  // O[-1]
        f32x2 hp0 = (w < NW - 1) ? halo[p][w + 1][0][lane] : one2;  // O[7]
        f32x2 hp1 = (w < NW - 1) ? halo[p][w + 1][1][lane] : one2;  // O[8]

        // rolling sweep, 9 static steps (k=-1..7):
        // N[k] = vsum3(hsum3(O[k-1..k+1])); hr[k] = hsum3(rcp(N[k]));
        // term t=k-1: s_t += clip(-C2*log2(a_t*(hr[t-1]+hr[t]+hr[t+1])));
        // then a_t <- N[t] (one step behind).
        f32x2 h_m = hsum3p(hm2);
        f32x2 h_c = hsum3p(hm1);
        f32x2 r_2 = {0.f, 0.f}, r_1 = r_2, n_prev = r_2;

#define STEPC(OP1) \
        f32x2 h_p = hsum3p(OP1); \
        f32x2 n   = pk_add(pk_add(h_m, h_c), h_p); \
        f32x2 rc; rc.x = __builtin_amdgcn_rcpf(n.x); \
                  rc.y = __builtin_amdgcn_rcpf(n.y); \
        f32x2 r_0 = hsum3p(rc);

#define STEP0(OP1) { STEPC(OP1) \
        n_prev = n; h_m = h_c; h_c = h_p; r_2 = r_1; r_1 = r_0; }

#define STEP(OP1, AT, ST, OKb) { STEPC(OP1) \
        if (OKb) { \
            f32x2 rs = pk_add(pk_add(r_2, r_1), r_0); \
            f32x2 PS = pk_mul(AT, rs); \
            f32x2 t; \
            t.x = fminf(fmaxf(-C2 * __builtin_amdgcn_logf(PS.x), 0.f), 1.f); \
            t.y = fminf(fmaxf(-C2 * __builtin_amdgcn_logf(PS.y), 0.f), 1.f); \
            ST = pk_add(ST, t); \
        } \
        AT = n_prev; \
        n_prev = n; h_m = h_c; h_c = h_p; r_2 = r_1; r_1 = r_0; }

        STEP0(a0)                  // k=-1
        STEP0(a1)                  // k=0
        STEP(a2,  a0, s0, ok0)     // k=1
        STEP(a3,  a1, s1, ok1)
        STEP(a4,  a2, s2, ok2)
        STEP(a5,  a3, s3, ok3)
        STEP(a6,  a4, s4, ok4)
        STEP(hp0, a5, s5, ok5)
        STEP(hp1, a6, s6, ok6)     // k=7
#undef STEP
#undef STEP0
#undef STEPC
        // no trailing barrier: parity buffer + next iter's barrier suffice
    }

    // store output: lanes 6..57 (cols [12,116) of tile), rows [12,44)
    if (lane >= 6 && lane <= 57) {
        int gx = gx0 + 2 * lane;
        if (gx >= 0 && gx + 1 < WW) {
            float* dst = out + (size_t)b * HH * WW;
#define STOREROW(I, SV) { int trow = r0 + (I); \
            if (trow >= HALO && trow < TH - HALO) { \
                int gy = gy0 + trow; \
                *reinterpret_cast<f32x2*>(&dst[(size_t)gy * WW + gx]) = SV; } }
            STOREROW(0, s0) STOREROW(1, s1) STOREROW(2, s2) STOREROW(3, s3)
            STOREROW(4, s4) STOREROW(5, s5) STOREROW(6, s6)
#undef STOREROW
        }
    }
}

extern "C" void kernel_launch(void* const* d_in, const int* in_sizes, int n_in,
                              void* d_out, int out_size, void* d_ws, size_t ws_size,
                              hipStream_t stream) {
    const float* x0 = (const float*)d_in[0];
    float* skel = (float*)d_out;
    skel_k<<<dim3(GX, GY, NB), dim3(512, 1, 1), 0, stream>>>(x0, skel);
}

// Round 13
// 28.684 us; speedup vs baseline: 1.4623x; 1.2506x over previous
//
#include <hip/hip_runtime.h>

// SmoothSkeletonDual: exp-domain, packed-FP32 (2 cols/lane) register-strip.
// T'_0 = exp2(-x*C1); T'_{j+1} = box3x3(T'_j) (unnormalized).
// term_j = clip(-C2*log2(T'_j(p) * sum_{3x3} 1/T'_{j+1}(q)), 0, 1)
// skel = sum_{j=0}^{10} term_j
//
// Tile 128 cols x 112 rows (output 104x88, halo 12): overcompute 1.57x
// (vs 2.15x at 56-row tile). 16 waves/block (1024 thr); wave w owns 7
// rows; lane owns 2 adjacent cols (f32x2, v_pk_*). Grid 240 blocks =
// one balanced round on 256 CUs. Waves 0/15 have no term rows -> run a
// box-only sweep (no rcp/log). Horizontal neighbors: DPP wave shifts;
// vertical halo via parity-double-buffered LDS, 1 barrier/iter.

#define HH 1024
#define WW 1024
#define NB 2
#define OTX 104
#define OTY 88
#define TW 128
#define TH 112            // RPW*NW
#define RPW 7
#define NW 16
#define HALO 12
#define GX 10             // ceil(1024/104)
#define GY 12             // ceil(1024/88)

constexpr float C1 = 28.85390081777927f;   // 1/(alpha*ln2)
constexpr float C2 = 0.03465735902799726f; // alpha*ln2

typedef float f32x2 __attribute__((ext_vector_type(2)));

__device__ __forceinline__ int mir(int i, int n) {
    return i < 0 ? -i : (i >= n ? 2 * n - 2 - i : i);
}
// lane i <- lane i-1 (WAVE_SHR1 0x138; lane 0 zero-filled)
__device__ __forceinline__ float nbrL(float v) {
    return __int_as_float(__builtin_amdgcn_update_dpp(
        0, __float_as_int(v), 0x138, 0xf, 0xf, true));
}
// lane i <- lane i+1 (WAVE_SHL1 0x130; lane 63 zero-filled)
__device__ __forceinline__ float nbrR(float v) {
    return __int_as_float(__builtin_amdgcn_update_dpp(
        0, __float_as_int(v), 0x130, 0xf, 0xf, true));
}

__device__ __forceinline__ f32x2 pk_add(f32x2 a, f32x2 b) {
    f32x2 d;
    asm("v_pk_add_f32 %0, %1, %2" : "=v"(d) : "v"(a), "v"(b));
    return d;
}
// d = a + swap(b):  d.lo = a.lo + b.hi ; d.hi = a.hi + b.lo
__device__ __forceinline__ f32x2 pk_add_swapB(f32x2 a, f32x2 b) {
    f32x2 d;
    asm("v_pk_add_f32 %0, %1, %2 op_sel:[0,1] op_sel_hi:[1,0]"
        : "=v"(d) : "v"(a), "v"(b));
    return d;
}
__device__ __forceinline__ f32x2 pk_mul(f32x2 a, f32x2 b) {
    f32x2 d;
    asm("v_pk_mul_f32 %0, %1, %2" : "=v"(d) : "v"(a), "v"(b));
    return d;
}

// 3-tap horizontal sum of the 128-col row: lane holds cols (2i, 2i+1).
__device__ __forceinline__ f32x2 hsum3p(f32x2 P) {
    f32x2 LR;
    LR.x = nbrL(P.y);                 // c(2i-1)
    LR.y = nbrR(P.x);                 // c(2i+2)
    f32x2 X = pk_add(LR, P);          // (L+lo, R+hi)
    return pk_add_swapB(X, P);        // (L+lo+hi, R+hi+lo)
}

__global__ __launch_bounds__(1024, 4) void skel_k(const float* __restrict__ x0,
                                                  float* __restrict__ out) {
    __shared__ f32x2 halo[2][NW][4][64];
    const int lane = threadIdx.x & 63;
    const int w    = threadIdx.x >> 6;
    const int tx = blockIdx.x, ty = blockIdx.y, b = blockIdx.z;
    const int gx0 = tx * OTX - HALO, gy0 = ty * OTY - HALO;
    const int r0 = w * RPW;          // first owned tile-row

    const float* src = x0 + (size_t)b * HH * WW;

    // owned rows (f32x2), named scalars
    f32x2 a0, a1, a2, a3, a4, a5, a6;
    const bool interior = (gx0 >= 0) && (gx0 + TW <= WW) &&
                          (gy0 >= 0) && (gy0 + TH <= HH);
    if (interior) {
        const float* base = src + (size_t)(gy0 + r0) * WW + gx0 + 2 * lane;
#define LOADROW(I, AV) { f32x2 v_ = *reinterpret_cast<const f32x2*>(base + (size_t)(I) * WW); \
        AV.x = __builtin_amdgcn_exp2f(v_.x * -C1); \
        AV.y = __builtin_amdgcn_exp2f(v_.y * -C1); }
        LOADROW(0, a0) LOADROW(1, a1) LOADROW(2, a2) LOADROW(3, a3)
        LOADROW(4, a4) LOADROW(5, a5) LOADROW(6, a6)
#undef LOADROW
    } else {
        const int mx0 = mir(gx0 + 2 * lane, WW);
        const int mx1 = mir(gx0 + 2 * lane + 1, WW);
#define LOADROW(I, AV) { int my_ = mir(gy0 + r0 + (I), HH); \
        const float* rr_ = src + (size_t)my_ * WW; \
        AV.x = __builtin_amdgcn_exp2f(rr_[mx0] * -C1); \
        AV.y = __builtin_amdgcn_exp2f(rr_[mx1] * -C1); }
        LOADROW(0, a0) LOADROW(1, a1) LOADROW(2, a2) LOADROW(3, a3)
        LOADROW(4, a4) LOADROW(5, a5) LOADROW(6, a6)
#undef LOADROW
    }

    f32x2 s0 = {0.f, 0.f}, s1 = s0, s2 = s0, s3 = s0, s4 = s0,
          s5 = s0, s6 = s0;

    // wave-uniform: does this wave own any term rows ([12, 100))?
    const bool hasTerm = (r0 + RPW - 1 >= HALO) && (r0 < TH - HALO);
    // per-row term masks
#define OKT(I) ((r0 + (I) >= HALO) && (r0 + (I) < TH - HALO))
    const bool ok0 = OKT(0), ok1 = OKT(1), ok2 = OKT(2), ok3 = OKT(3),
               ok4 = OKT(4), ok5 = OKT(5), ok6 = OKT(6);
#undef OKT

    #pragma unroll 1
    for (int j = 0; j < 11; ++j) {
        const int p = j & 1;
        halo[p][w][0][lane] = a0;
        halo[p][w][1][lane] = a1;
        halo[p][w][2][lane] = a5;
        halo[p][w][3][lane] = a6;
        __syncthreads();
        f32x2 one2 = {1.f, 1.f};
        f32x2 hm2 = (w > 0)      ? halo[p][w - 1][2][lane] : one2;  // O[-2]
        f32x2 hm1 = (w > 0)      ? halo[p][w - 1][3][lane] : one2;  // O[-1]
        f32x2 hp0 = (w < NW - 1) ? halo[p][w + 1][0][lane] : one2;  // O[7]
        f32x2 hp1 = (w < NW - 1) ? halo[p][w + 1][1][lane] : one2;  // O[8]

        f32x2 h_m = hsum3p(hm2);
        f32x2 h_c = hsum3p(hm1);
        f32x2 n_prev = {0.f, 0.f};

        if (hasTerm) {
            // full sweep: box + rcp-box + term (9 static steps, k=-1..7)
            f32x2 r_2 = {0.f, 0.f}, r_1 = r_2;
#define STEPC(OP1) \
            f32x2 h_p = hsum3p(OP1); \
            f32x2 n   = pk_add(pk_add(h_m, h_c), h_p); \
            f32x2 rc; rc.x = __builtin_amdgcn_rcpf(n.x); \
                      rc.y = __builtin_amdgcn_rcpf(n.y); \
            f32x2 r_0 = hsum3p(rc);
#define STEP0(OP1) { STEPC(OP1) \
            n_prev = n; h_m = h_c; h_c = h_p; r_2 = r_1; r_1 = r_0; }
#define STEP(OP1, AT, ST, OKb) { STEPC(OP1) \
            if (OKb) { \
                f32x2 rs = pk_add(pk_add(r_2, r_1), r_0); \
                f32x2 PS = pk_mul(AT, rs); \
                f32x2 t; \
                t.x = __builtin_amdgcn_fmed3f(-C2 * __builtin_amdgcn_logf(PS.x), 0.f, 1.f); \
                t.y = __builtin_amdgcn_fmed3f(-C2 * __builtin_amdgcn_logf(PS.y), 0.f, 1.f); \
                ST = pk_add(ST, t); \
            } \
            AT = n_prev; \
            n_prev = n; h_m = h_c; h_c = h_p; r_2 = r_1; r_1 = r_0; }

            STEP0(a0)                  // k=-1
            STEP0(a1)                  // k=0
            STEP(a2,  a0, s0, ok0)     // k=1
            STEP(a3,  a1, s1, ok1)
            STEP(a4,  a2, s2, ok2)
            STEP(a5,  a3, s3, ok3)
            STEP(a6,  a4, s4, ok4)
            STEP(hp0, a5, s5, ok5)
            STEP(hp1, a6, s6, ok6)     // k=7
#undef STEP
#undef STEP0
#undef STEPC
        } else {
            // box-only sweep (waves 0 and NW-1: no term rows)
#define BSTEP0(OP1) { f32x2 h_p = hsum3p(OP1); \
            f32x2 n = pk_add(pk_add(h_m, h_c), h_p); \
            n_prev = n; h_m = h_c; h_c = h_p; }
#define BSTEP(OP1, AT) { f32x2 h_p = hsum3p(OP1); \
            f32x2 n = pk_add(pk_add(h_m, h_c), h_p); \
            AT = n_prev; n_prev = n; h_m = h_c; h_c = h_p; }
            BSTEP0(a0)
            BSTEP0(a1)
            BSTEP(a2,  a0)
            BSTEP(a3,  a1)
            BSTEP(a4,  a2)
            BSTEP(a5,  a3)
            BSTEP(a6,  a4)
            BSTEP(hp0, a5)
            BSTEP(hp1, a6)
#undef BSTEP
#undef BSTEP0
        }
        // no trailing barrier: parity buffer + next iter's barrier suffice
    }

    // store output: lanes 6..57 (tile cols [12,116)), rows [12, 100)
    if (hasTerm && lane >= 6 && lane <= 57) {
        int gx = gx0 + 2 * lane;
        if (gx >= 0 && gx + 1 < WW) {
            float* dst = out + (size_t)b * HH * WW;
#define STOREROW(I, SV) { int trow = r0 + (I); \
            if (trow >= HALO && trow < TH - HALO) { \
                int gy = gy0 + trow; \
                if (gy < HH) \
                    *reinterpret_cast<f32x2*>(&dst[(size_t)gy * WW + gx]) = SV; } }
            STOREROW(0, s0) STOREROW(1, s1) STOREROW(2, s2) STOREROW(3, s3)
            STOREROW(4, s4) STOREROW(5, s5) STOREROW(6, s6)
#undef STOREROW
        }
    }
}

extern "C" void kernel_launch(void* const* d_in, const int* in_sizes, int n_in,
                              void* d_out, int out_size, void* d_ws, size_t ws_size,
                              hipStream_t stream) {
    const float* x0 = (const float*)d_in[0];
    float* skel = (float*)d_out;
    skel_k<<<dim3(GX, GY, NB), dim3(1024, 1, 1), 0, stream>>>(x0, skel);
}